// Round 1
// baseline (112.213 us; speedup 1.0000x reference)
//
#include <hip/hip_runtime.h>

#define IH 2048
#define IW 2048
#define NB 8

__global__ __launch_bounds__(256) void demosaic_rg_kernel(
    const float* __restrict__ img, float* __restrict__ out) {
    int tid = blockIdx.x * blockDim.x + threadIdx.x;
    int j = tid & 1023;           // quad col (x0 = 2j)
    int i = (tid >> 10) & 1023;   // quad row (y0 = 2i)
    int b = tid >> 20;            // batch
    int x0 = j << 1, y0 = i << 1;

    const float* p = img + (size_t)b * IH * IW;

    int ym1 = (y0 == 0) ? 1 : y0 - 1;            // top clamp/reflect -> 1
    int yp2 = (y0 == IH - 2) ? IH - 2 : y0 + 2;  // bottom clamp/reflect -> 2046
    int xm1 = (x0 == 0) ? 1 : x0 - 1;
    int xp2 = (x0 == IW - 2) ? IW - 2 : x0 + 2;

    const float* rA = p + (size_t)ym1 * IW;       // row y0-1 (clamped)
    const float* r0 = p + (size_t)y0 * IW;        // row y0
    const float* r1 = p + (size_t)(y0 + 1) * IW;  // row y0+1
    const float* rB = p + (size_t)yp2 * IW;       // row y0+2 (clamped)

    float a_m1 = rA[xm1], a_0 = rA[x0], a_1 = rA[x0 + 1];
    float c_m1 = r0[xm1], c_0 = r0[x0], c_1 = r0[x0 + 1], c_2 = r0[xp2];
    float d_m1 = r1[xm1], d_0 = r1[x0], d_1 = r1[x0 + 1], d_2 = r1[xp2];
    float e_0 = rB[x0], e_1 = rB[x0 + 1], e_2 = rB[xp2];

    // Red (exact at odd,odd = d_1)
    float R00 = 0.25f * (a_m1 + a_1 + d_m1 + d_1);
    float R01 = 0.5f * (a_1 + d_1);
    float R10 = 0.5f * (d_m1 + d_1);
    float R11 = d_1;

    // Green (exact at (even,odd)=c_1 and (odd,even)=d_0)
    float G00 = 0.25f * (a_0 + d_0 + c_m1 + c_1);
    float G01 = c_1;
    float G10 = d_0;
    float G11 = 0.25f * (c_1 + e_1 + d_0 + d_2);

    // Blue (exact at even,even = c_0)
    float B00 = c_0;
    float B01 = 0.5f * (c_0 + c_2);
    float B10 = 0.5f * (c_0 + e_0);
    float B11 = 0.25f * (c_0 + c_2 + e_0 + e_2);

    size_t base = (size_t)b * 3 * IH * IW;
    float* oR = out + base;
    float* oG = oR + (size_t)IH * IW;
    float* oB = oG + (size_t)IH * IW;
    size_t off0 = (size_t)y0 * IW + x0;
    size_t off1 = off0 + IW;

    *(float2*)(oR + off0) = make_float2(R00, R01);
    *(float2*)(oR + off1) = make_float2(R10, R11);
    *(float2*)(oG + off0) = make_float2(G00, G01);
    *(float2*)(oG + off1) = make_float2(G10, G11);
    *(float2*)(oB + off0) = make_float2(B00, B01);
    *(float2*)(oB + off1) = make_float2(B10, B11);
}

extern "C" void kernel_launch(void* const* d_in, const int* in_sizes, int n_in,
                              void* d_out, int out_size, void* d_ws, size_t ws_size,
                              hipStream_t stream) {
    const float* img = (const float*)d_in[0];
    float* out = (float*)d_out;
    // one thread per 2x2 quad: 8 * 1024 * 1024 quads
    int total = NB * (IH / 2) * (IW / 2);
    int block = 256;
    int grid = total / block;
    demosaic_rg_kernel<<<grid, block, 0, stream>>>(img, out);
}

// Round 2
// 106.623 us; speedup vs baseline: 1.0524x; 1.0524x over previous
//
#include <hip/hip_runtime.h>

#define IH 2048
#define IW 2048
#define NB 8

__global__ __launch_bounds__(256) void demosaic_rg_kernel(
    const float* __restrict__ img, float* __restrict__ out) {
    int tid = blockIdx.x * blockDim.x + threadIdx.x;
    int j = tid & 511;            // x-group: 4 output cols (2 quads)
    int i = (tid >> 9) & 1023;    // quad row (y0 = 2i)
    int b = tid >> 19;            // batch
    int x0 = j << 2, y0 = i << 1;

    const float* p = img + (size_t)b * IH * IW;

    int ym1 = (y0 == 0) ? 1 : y0 - 1;            // top edge -> 1
    int yp2 = (y0 == IH - 2) ? IH - 2 : y0 + 2;  // bottom edge -> 2046
    int xm1 = (x0 == 0) ? 1 : x0 - 1;            // left edge -> 1
    int xp4 = (x0 == IW - 4) ? IW - 2 : x0 + 4;  // right edge -> 2046

    const float* rA = p + (size_t)ym1 * IW;       // row y0-1 (clamped)
    const float* r0 = p + (size_t)y0 * IW;        // row y0
    const float* r1 = p + (size_t)(y0 + 1) * IW;  // row y0+1
    const float* rB = p + (size_t)yp2 * IW;       // row y0+2 (clamped)

    float4 A = *(const float4*)(rA + x0);   // a[x0..x0+3]
    float4 C = *(const float4*)(r0 + x0);
    float4 D = *(const float4*)(r1 + x0);
    float4 E = *(const float4*)(rB + x0);
    float a_m1 = rA[xm1];
    float c_m1 = r0[xm1], c_p4 = r0[xp4];
    float d_m1 = r1[xm1], d_p4 = r1[xp4];
    float e_p4 = rB[xp4];

    // ---- quad 0 (output cols x0, x0+1) ----
    // a_m1, a0=A.x, a1=A.y | c_m1, c0=C.x, c1=C.y, c2=C.z
    // d_m1, d0=D.x, d1=D.y, d2=D.z | e0=E.x, e1=E.y, e2=E.z
    float R00_0 = 0.25f * (a_m1 + A.y + d_m1 + D.y);
    float R01_0 = 0.5f * (A.y + D.y);
    float R10_0 = 0.5f * (d_m1 + D.y);
    float R11_0 = D.y;

    float G00_0 = 0.25f * (A.x + D.x + c_m1 + C.y);
    float G01_0 = C.y;
    float G10_0 = D.x;
    float G11_0 = 0.25f * (C.y + E.y + D.x + D.z);

    float B00_0 = C.x;
    float B01_0 = 0.5f * (C.x + C.z);
    float B10_0 = 0.5f * (C.x + E.x);
    float B11_0 = 0.25f * (C.x + C.z + E.x + E.z);

    // ---- quad 1 (output cols x0+2, x0+3) ----
    // a_m1=A.y, a0=A.z, a1=A.w | c_m1=C.y, c0=C.z, c1=C.w, c2=c_p4
    // d_m1=D.y, d0=D.z, d1=D.w, d2=d_p4 | e0=E.z, e1=E.w, e2=e_p4
    float R00_1 = 0.25f * (A.y + A.w + D.y + D.w);
    float R01_1 = 0.5f * (A.w + D.w);
    float R10_1 = 0.5f * (D.y + D.w);
    float R11_1 = D.w;

    float G00_1 = 0.25f * (A.z + D.z + C.y + C.w);
    float G01_1 = C.w;
    float G10_1 = D.z;
    float G11_1 = 0.25f * (C.w + E.w + D.z + d_p4);

    float B00_1 = C.z;
    float B01_1 = 0.5f * (C.z + c_p4);
    float B10_1 = 0.5f * (C.z + E.z);
    float B11_1 = 0.25f * (C.z + c_p4 + E.z + e_p4);

    size_t base = (size_t)b * 3 * IH * IW;
    float* oR = out + base;
    float* oG = oR + (size_t)IH * IW;
    float* oB = oG + (size_t)IH * IW;
    size_t off0 = (size_t)y0 * IW + x0;
    size_t off1 = off0 + IW;

    *(float4*)(oR + off0) = make_float4(R00_0, R01_0, R00_1, R01_1);
    *(float4*)(oR + off1) = make_float4(R10_0, R11_0, R10_1, R11_1);
    *(float4*)(oG + off0) = make_float4(G00_0, G01_0, G00_1, G01_1);
    *(float4*)(oG + off1) = make_float4(G10_0, G11_0, G10_1, G11_1);
    *(float4*)(oB + off0) = make_float4(B00_0, B01_0, B00_1, B01_1);
    *(float4*)(oB + off1) = make_float4(B10_0, B11_0, B10_1, B11_1);
}

extern "C" void kernel_launch(void* const* d_in, const int* in_sizes, int n_in,
                              void* d_out, int out_size, void* d_ws, size_t ws_size,
                              hipStream_t stream) {
    const float* img = (const float*)d_in[0];
    float* out = (float*)d_out;
    // one thread per 2x4 output region: 8 * 1024 * 512 threads
    int total = NB * (IH / 2) * (IW / 4);
    int block = 256;
    int grid = total / block;
    demosaic_rg_kernel<<<grid, block, 0, stream>>>(img, out);
}

// Round 4
// 101.588 us; speedup vs baseline: 1.1046x; 1.0496x over previous
//
#include <hip/hip_runtime.h>

#define IH 2048
#define IW 2048
#define NB 8

typedef float vfloat4 __attribute__((ext_vector_type(4)));

__device__ __forceinline__ void nt_store4(float* p, float a, float b, float c, float d) {
    vfloat4 v = {a, b, c, d};
    __builtin_nontemporal_store(v, (vfloat4*)p);
}

__global__ __launch_bounds__(256) void demosaic_rg_kernel(
    const float* __restrict__ img, float* __restrict__ out) {
    int tid = blockIdx.x * blockDim.x + threadIdx.x;
    int j = tid & 511;            // x-group: 4 output cols (2 quads)
    int i = (tid >> 9) & 1023;    // quad row (y0 = 2i)
    int b = tid >> 19;            // batch
    int x0 = j << 2, y0 = i << 1;

    const float* p = img + (size_t)b * IH * IW;

    int ym1 = (y0 == 0) ? 1 : y0 - 1;            // top edge -> 1
    int yp2 = (y0 == IH - 2) ? IH - 2 : y0 + 2;  // bottom edge -> 2046
    int xm1 = (x0 == 0) ? 1 : x0 - 1;            // left edge -> 1
    int xp4 = (x0 == IW - 4) ? IW - 2 : x0 + 4;  // right edge -> 2046

    const float* rA = p + (size_t)ym1 * IW;       // row y0-1 (clamped)
    const float* r0 = p + (size_t)y0 * IW;        // row y0
    const float* r1 = p + (size_t)(y0 + 1) * IW;  // row y0+1
    const float* rB = p + (size_t)yp2 * IW;       // row y0+2 (clamped)

    float4 A = *(const float4*)(rA + x0);   // a[x0..x0+3]
    float4 C = *(const float4*)(r0 + x0);
    float4 D = *(const float4*)(r1 + x0);
    float4 E = *(const float4*)(rB + x0);
    float a_m1 = rA[xm1];
    float c_m1 = r0[xm1], c_p4 = r0[xp4];
    float d_m1 = r1[xm1], d_p4 = r1[xp4];
    float e_p4 = rB[xp4];

    // ---- quad 0 (output cols x0, x0+1) ----
    float R00_0 = 0.25f * (a_m1 + A.y + d_m1 + D.y);
    float R01_0 = 0.5f * (A.y + D.y);
    float R10_0 = 0.5f * (d_m1 + D.y);
    float R11_0 = D.y;

    float G00_0 = 0.25f * (A.x + D.x + c_m1 + C.y);
    float G01_0 = C.y;
    float G10_0 = D.x;
    float G11_0 = 0.25f * (C.y + E.y + D.x + D.z);

    float B00_0 = C.x;
    float B01_0 = 0.5f * (C.x + C.z);
    float B10_0 = 0.5f * (C.x + E.x);
    float B11_0 = 0.25f * (C.x + C.z + E.x + E.z);

    // ---- quad 1 (output cols x0+2, x0+3) ----
    float R00_1 = 0.25f * (A.y + A.w + D.y + D.w);
    float R01_1 = 0.5f * (A.w + D.w);
    float R10_1 = 0.5f * (D.y + D.w);
    float R11_1 = D.w;

    float G00_1 = 0.25f * (A.z + D.z + C.y + C.w);
    float G01_1 = C.w;
    float G10_1 = D.z;
    float G11_1 = 0.25f * (C.w + E.w + D.z + d_p4);

    float B00_1 = C.z;
    float B01_1 = 0.5f * (C.z + c_p4);
    float B10_1 = 0.5f * (C.z + E.z);
    float B11_1 = 0.25f * (C.z + c_p4 + E.z + e_p4);

    size_t base = (size_t)b * 3 * IH * IW;
    float* oR = out + base;
    float* oG = oR + (size_t)IH * IW;
    float* oB = oG + (size_t)IH * IW;
    size_t off0 = (size_t)y0 * IW + x0;
    size_t off1 = off0 + IW;

    // Non-temporal: output is write-once, keep it out of L2/L3 so the
    // input (128 MB, 2x reuse across quad-rows) stays L3-resident.
    nt_store4(oR + off0, R00_0, R01_0, R00_1, R01_1);
    nt_store4(oR + off1, R10_0, R11_0, R10_1, R11_1);
    nt_store4(oG + off0, G00_0, G01_0, G00_1, G01_1);
    nt_store4(oG + off1, G10_0, G11_0, G10_1, G11_1);
    nt_store4(oB + off0, B00_0, B01_0, B00_1, B01_1);
    nt_store4(oB + off1, B10_0, B11_0, B10_1, B11_1);
}

extern "C" void kernel_launch(void* const* d_in, const int* in_sizes, int n_in,
                              void* d_out, int out_size, void* d_ws, size_t ws_size,
                              hipStream_t stream) {
    const float* img = (const float*)d_in[0];
    float* out = (float*)d_out;
    // one thread per 2x4 output region: 8 * 1024 * 512 threads
    int total = NB * (IH / 2) * (IW / 4);
    int block = 256;
    int grid = total / block;
    demosaic_rg_kernel<<<grid, block, 0, stream>>>(img, out);
}

// Round 5
// 79.178 us; speedup vs baseline: 1.4172x; 1.2830x over previous
//
#include <hip/hip_runtime.h>

#define IH 2048
#define IW 2048
#define NB 8

typedef float vfloat4 __attribute__((ext_vector_type(4)));

__device__ __forceinline__ void nt_store4(float* p, float a, float b, float c, float d) {
    vfloat4 v = {a, b, c, d};
    __builtin_nontemporal_store(v, (vfloat4*)p);
}

__global__ __launch_bounds__(256) void demosaic_rg_kernel(
    const float* __restrict__ img, float* __restrict__ out) {
    // XCD-chunked swizzle (T1): HW round-robins blockIdx across 8 XCDs.
    // Remap so each XCD gets a contiguous 2048-block chunk (= one batch
    // image) -> vertical quad-row reuse hits that XCD's private L2.
    // nwg = 16384, 16384 % 8 == 0 -> simple bijective form.
    int bid = blockIdx.x;
    int nbid = (bid & 7) * 2048 + (bid >> 3);
    int tid = nbid * 256 + (int)threadIdx.x;

    int j = tid & 511;            // x-group: 4 output cols (2 quads)
    int i = (tid >> 9) & 1023;    // quad row (y0 = 2i)
    int b = tid >> 19;            // batch
    int x0 = j << 2, y0 = i << 1;

    const float* p = img + (size_t)b * IH * IW;

    int ym1 = (y0 == 0) ? 1 : y0 - 1;            // top edge -> 1
    int yp2 = (y0 == IH - 2) ? IH - 2 : y0 + 2;  // bottom edge -> 2046
    int xm1 = (x0 == 0) ? 1 : x0 - 1;            // left edge -> 1
    int xp4 = (x0 == IW - 4) ? IW - 2 : x0 + 4;  // right edge -> 2046

    const float* rA = p + (size_t)ym1 * IW;       // row y0-1 (clamped)
    const float* r0 = p + (size_t)y0 * IW;        // row y0
    const float* r1 = p + (size_t)(y0 + 1) * IW;  // row y0+1
    const float* rB = p + (size_t)yp2 * IW;       // row y0+2 (clamped)

    float4 A = *(const float4*)(rA + x0);   // a[x0..x0+3]
    float4 C = *(const float4*)(r0 + x0);
    float4 D = *(const float4*)(r1 + x0);
    float4 E = *(const float4*)(rB + x0);
    float a_m1 = rA[xm1];
    float c_m1 = r0[xm1], c_p4 = r0[xp4];
    float d_m1 = r1[xm1], d_p4 = r1[xp4];
    float e_p4 = rB[xp4];

    // ---- quad 0 (output cols x0, x0+1) ----
    float R00_0 = 0.25f * (a_m1 + A.y + d_m1 + D.y);
    float R01_0 = 0.5f * (A.y + D.y);
    float R10_0 = 0.5f * (d_m1 + D.y);
    float R11_0 = D.y;

    float G00_0 = 0.25f * (A.x + D.x + c_m1 + C.y);
    float G01_0 = C.y;
    float G10_0 = D.x;
    float G11_0 = 0.25f * (C.y + E.y + D.x + D.z);

    float B00_0 = C.x;
    float B01_0 = 0.5f * (C.x + C.z);
    float B10_0 = 0.5f * (C.x + E.x);
    float B11_0 = 0.25f * (C.x + C.z + E.x + E.z);

    // ---- quad 1 (output cols x0+2, x0+3) ----
    float R00_1 = 0.25f * (A.y + A.w + D.y + D.w);
    float R01_1 = 0.5f * (A.w + D.w);
    float R10_1 = 0.5f * (D.y + D.w);
    float R11_1 = D.w;

    float G00_1 = 0.25f * (A.z + D.z + C.y + C.w);
    float G01_1 = C.w;
    float G10_1 = D.z;
    float G11_1 = 0.25f * (C.w + E.w + D.z + d_p4);

    float B00_1 = C.z;
    float B01_1 = 0.5f * (C.z + c_p4);
    float B10_1 = 0.5f * (C.z + E.z);
    float B11_1 = 0.25f * (C.z + c_p4 + E.z + e_p4);

    size_t base = (size_t)b * 3 * IH * IW;
    float* oR = out + base;
    float* oG = oR + (size_t)IH * IW;
    float* oB = oG + (size_t)IH * IW;
    size_t off0 = (size_t)y0 * IW + x0;
    size_t off1 = off0 + IW;

    // Non-temporal: output is write-once, keep it out of L2/L3 so the
    // input rows (2x vertical reuse) stay cache-resident.
    nt_store4(oR + off0, R00_0, R01_0, R00_1, R01_1);
    nt_store4(oR + off1, R10_0, R11_0, R10_1, R11_1);
    nt_store4(oG + off0, G00_0, G01_0, G00_1, G01_1);
    nt_store4(oG + off1, G10_0, G11_0, G10_1, G11_1);
    nt_store4(oB + off0, B00_0, B01_0, B00_1, B01_1);
    nt_store4(oB + off1, B10_0, B11_0, B10_1, B11_1);
}

extern "C" void kernel_launch(void* const* d_in, const int* in_sizes, int n_in,
                              void* d_out, int out_size, void* d_ws, size_t ws_size,
                              hipStream_t stream) {
    const float* img = (const float*)d_in[0];
    float* out = (float*)d_out;
    // one thread per 2x4 output region: 8 * 1024 * 512 threads
    int total = NB * (IH / 2) * (IW / 4);
    int block = 256;
    int grid = total / block;  // 16384
    demosaic_rg_kernel<<<grid, block, 0, stream>>>(img, out);
}